// Round 4
// baseline (186.369 us; speedup 1.0000x reference)
//
#include <hip/hip_runtime.h>
#include <hip/hip_fp8.h>
#include <hip/hip_fp16.h>

// SumLayer: weighted logsumexp over E children per node.
// N=32768, E=32, B=256, MAX_ELS=65536.
//
// R7 design. History:
//  R0-R2: fetch-bound (3.7 TB/s L2-miss). R3: fp8 G (16MB). R4: chunk-major
//  G[chunk][row] + XCD slicing + WC=u16 cid|f16 w -> FETCH 337->25MB, 44us.
//  R5: 2x instr reduction + 16-deep pipeline: null -> not instr/MLP bound then.
//  R6: 64B requests (CHUNK_COLS=64, NCHUNK=4, slice 4MB on 2 XCDs): only -15%
//  (~40us), so pure request-count ceiling is out. VGPR=36 says the compiler
//  kept ~4 loads in flight behind a ds_read->global_load dependency chain ->
//  revised theory: dependent-issue LATENCY bound.
// R7 levers:
//  1) no LDS, no syncthreads: each lane loads its node's 32 wc entries
//     directly to 8 VGPR vectors (nontemporal dwordx4; 4-lane dups coalesce).
//  2) explicit 2x8 double-buffered gather pipeline, named regs -> 16
//     outstanding 64B gathers/wave, addresses ready in-register.
//  3) pre-passes merged into one kernel (block-role split).
// Predicted: sum_main ~40 -> 24-28us (VGPR ~130, LDS 0), total ~153-160us.

constexpr int NN = 32768;
constexpr int EE = 32;
constexpr int BB = 256;
constexpr int MAX_ELS = 65536;

constexpr int NCHUNK = 4;                 // column chunks; slice on 2 XCDs
constexpr int CHUNK_COLS = 64;            // fp8 bytes per row per chunk
constexpr size_t SLICE_BYTES = (size_t)MAX_ELS * CHUNK_COLS;  // 4 MB
constexpr int NPB = 64;                   // nodes per block (main kernel)

typedef float floatx2 __attribute__((ext_vector_type(2)));
typedef float f32x4 __attribute__((ext_vector_type(4)));
typedef unsigned int u32x4 __attribute__((ext_vector_type(4)));

__device__ inline int pack4_fp8(float4 v) {
    const int a = __hip_cvt_float_to_fp8(__expf(v.x), __HIP_SATFINITE, __HIP_E4M3);
    const int b = __hip_cvt_float_to_fp8(__expf(v.y), __HIP_SATFINITE, __HIP_E4M3);
    const int c = __hip_cvt_float_to_fp8(__expf(v.z), __HIP_SATFINITE, __HIP_E4M3);
    const int d = __hip_cvt_float_to_fp8(__expf(v.w), __HIP_SATFINITE, __HIP_E4M3);
    return a | (b << 8) | (c << 16) | (d << 24);
}

// ---- merged pre-pass ----
// blocks [0,4096):  G[c][r][0..63] = fp8(exp(element_mars[r][c*64..+63]))
// blocks [4096,8192): WC[i] = (cids[i] as u16) | (f16(params[pids[i]]) << 16)
__global__ __launch_bounds__(256)
void prep_kernel(const float4* __restrict__ em, const float* __restrict__ params,
                 const int* __restrict__ cids, const int* __restrict__ pids,
                 unsigned char* __restrict__ G, unsigned int* __restrict__ WC)
{
    if (blockIdx.x < 4096) {
        const int wid  = blockIdx.x * 4 + (threadIdx.x >> 6);
        const int lane = threadIdx.x & 63;
        const int c    = wid & 3;
        const int rg   = wid >> 2;                  // [0, 4096)
        const int r    = rg * 16 + (lane >> 2);
        const int q    = lane & 3;

        const float4* src = em + (size_t)r * 64 + c * 16 + q * 4;
        const float4 v0 = src[0], v1 = src[1], v2 = src[2], v3 = src[3];
        int4 o;
        o.x = pack4_fp8(v0);
        o.y = pack4_fp8(v1);
        o.z = pack4_fp8(v2);
        o.w = pack4_fp8(v3);
        *reinterpret_cast<int4*>(G + (size_t)c * SLICE_BYTES
                                   + (size_t)r * CHUNK_COLS + q * 16) = o;
    } else {
        const int i = (blockIdx.x - 4096) * 256 + threadIdx.x;
        const unsigned int cid = (unsigned int)cids[i] & 0xFFFFu;   // MAX_ELS = 2^16
        const float w = params[pids[i]];
        const unsigned int h = (unsigned int)__half_as_ushort(__float2half(w));
        WC[i] = cid | (h << 16);
    }
}

// ---- main: 64 nodes/block x 64 cols; chunk = blockIdx%4 -> slice on 2 XCDs ----
// 16 nodes/wave, 4 lanes/node, one 64B request per (node,e).
// wc entries register-resident; 2x8 double-buffered gather pipeline.
__global__ __launch_bounds__(256)
void sum_main_kernel(const unsigned char* __restrict__ G, const unsigned int* __restrict__ WC,
                     const int* __restrict__ nids, float* __restrict__ out)
{
    const int chunk = blockIdx.x & (NCHUNK - 1);
    const int g     = blockIdx.x >> 2;          // node-group of 64
    const int tid   = threadIdx.x;
    const int lane  = tid & 63;
    const int nl    = (tid >> 6) * 16 + (lane >> 2);   // node-local 0..63
    const int l4    = lane & 3;                        // 16 cols of 64-col slice
    const int n     = g * NPB + nl;

    const unsigned char* Gs = G + (size_t)chunk * SLICE_BYTES + l4 * 16;

    // node's 32 packed (cid,w) entries -> 8 register vectors.
    // 4 lanes/node issue the same addresses (coalescer merges); nontemporal
    // so the WC stream doesn't evict the G slice from this XCD's L2.
    const u32x4* wcp = reinterpret_cast<const u32x4*>(WC) + (size_t)n * 8;
    const u32x4 wc0 = __builtin_nontemporal_load(wcp + 0);
    const u32x4 wc1 = __builtin_nontemporal_load(wcp + 1);
    const u32x4 wc2 = __builtin_nontemporal_load(wcp + 2);
    const u32x4 wc3 = __builtin_nontemporal_load(wcp + 3);
    const u32x4 wc4 = __builtin_nontemporal_load(wcp + 4);
    const u32x4 wc5 = __builtin_nontemporal_load(wcp + 5);
    const u32x4 wc6 = __builtin_nontemporal_load(wcp + 6);
    const u32x4 wc7 = __builtin_nontemporal_load(wcp + 7);

    float acc[16];
#pragma unroll
    for (int k = 0; k < 16; ++k) acc[k] = 0.f;

#define LDG(WCE) (*reinterpret_cast<const u32x4*>( \
        Gs + ((size_t)((WCE) & 0xFFFFu) << 6)))

#define FMAV(U, WCE) do {                                                       \
    const float w_ = __half2float(__ushort_as_half(                             \
        (unsigned short)((WCE) >> 16)));                                        \
    const floatx2 p0 = __builtin_amdgcn_cvt_pk_f32_fp8((U).x, false);           \
    const floatx2 p1 = __builtin_amdgcn_cvt_pk_f32_fp8((U).x, true);            \
    const floatx2 p2 = __builtin_amdgcn_cvt_pk_f32_fp8((U).y, false);           \
    const floatx2 p3 = __builtin_amdgcn_cvt_pk_f32_fp8((U).y, true);            \
    const floatx2 p4 = __builtin_amdgcn_cvt_pk_f32_fp8((U).z, false);           \
    const floatx2 p5 = __builtin_amdgcn_cvt_pk_f32_fp8((U).z, true);            \
    const floatx2 p6 = __builtin_amdgcn_cvt_pk_f32_fp8((U).w, false);           \
    const floatx2 p7 = __builtin_amdgcn_cvt_pk_f32_fp8((U).w, true);            \
    acc[0]  = fmaf(p0.x, w_, acc[0]);                                           \
    acc[1]  = fmaf(p0.y, w_, acc[1]);                                           \
    acc[2]  = fmaf(p1.x, w_, acc[2]);                                           \
    acc[3]  = fmaf(p1.y, w_, acc[3]);                                           \
    acc[4]  = fmaf(p2.x, w_, acc[4]);                                           \
    acc[5]  = fmaf(p2.y, w_, acc[5]);                                           \
    acc[6]  = fmaf(p3.x, w_, acc[6]);                                           \
    acc[7]  = fmaf(p3.y, w_, acc[7]);                                           \
    acc[8]  = fmaf(p4.x, w_, acc[8]);                                           \
    acc[9]  = fmaf(p4.y, w_, acc[9]);                                           \
    acc[10] = fmaf(p5.x, w_, acc[10]);                                          \
    acc[11] = fmaf(p5.y, w_, acc[11]);                                          \
    acc[12] = fmaf(p6.x, w_, acc[12]);                                          \
    acc[13] = fmaf(p6.y, w_, acc[13]);                                          \
    acc[14] = fmaf(p7.x, w_, acc[14]);                                          \
    acc[15] = fmaf(p7.y, w_, acc[15]);                                          \
} while (0)

    u32x4 a0, a1, a2, a3, a4, a5, a6, a7;
    u32x4 b0, b1, b2, b3, b4, b5, b6, b7;

    // fill both buffers: 16 gathers in flight
    a0 = LDG(wc0.x); a1 = LDG(wc0.y); a2 = LDG(wc0.z); a3 = LDG(wc0.w);
    a4 = LDG(wc1.x); a5 = LDG(wc1.y); a6 = LDG(wc1.z); a7 = LDG(wc1.w);
    b0 = LDG(wc2.x); b1 = LDG(wc2.y); b2 = LDG(wc2.z); b3 = LDG(wc2.w);
    b4 = LDG(wc3.x); b5 = LDG(wc3.y); b6 = LDG(wc3.z); b7 = LDG(wc3.w);

    FMAV(a0, wc0.x); FMAV(a1, wc0.y); FMAV(a2, wc0.z); FMAV(a3, wc0.w);
    FMAV(a4, wc1.x); FMAV(a5, wc1.y); FMAV(a6, wc1.z); FMAV(a7, wc1.w);

    a0 = LDG(wc4.x); a1 = LDG(wc4.y); a2 = LDG(wc4.z); a3 = LDG(wc4.w);
    a4 = LDG(wc5.x); a5 = LDG(wc5.y); a6 = LDG(wc5.z); a7 = LDG(wc5.w);

    FMAV(b0, wc2.x); FMAV(b1, wc2.y); FMAV(b2, wc2.z); FMAV(b3, wc2.w);
    FMAV(b4, wc3.x); FMAV(b5, wc3.y); FMAV(b6, wc3.z); FMAV(b7, wc3.w);

    b0 = LDG(wc6.x); b1 = LDG(wc6.y); b2 = LDG(wc6.z); b3 = LDG(wc6.w);
    b4 = LDG(wc7.x); b5 = LDG(wc7.y); b6 = LDG(wc7.z); b7 = LDG(wc7.w);

    FMAV(a0, wc4.x); FMAV(a1, wc4.y); FMAV(a2, wc4.z); FMAV(a3, wc4.w);
    FMAV(a4, wc5.x); FMAV(a5, wc5.y); FMAV(a6, wc5.z); FMAV(a7, wc5.w);

    FMAV(b0, wc6.x); FMAV(b1, wc6.y); FMAV(b2, wc6.z); FMAV(b3, wc6.w);
    FMAV(b4, wc7.x); FMAV(b5, wc7.y); FMAV(b6, wc7.z); FMAV(b7, wc7.w);

#undef LDG
#undef FMAV

    f32x4 r0, r1, r2, r3;
    r0.x = __logf(fmaxf(acc[0],  1e-10f));
    r0.y = __logf(fmaxf(acc[1],  1e-10f));
    r0.z = __logf(fmaxf(acc[2],  1e-10f));
    r0.w = __logf(fmaxf(acc[3],  1e-10f));
    r1.x = __logf(fmaxf(acc[4],  1e-10f));
    r1.y = __logf(fmaxf(acc[5],  1e-10f));
    r1.z = __logf(fmaxf(acc[6],  1e-10f));
    r1.w = __logf(fmaxf(acc[7],  1e-10f));
    r2.x = __logf(fmaxf(acc[8],  1e-10f));
    r2.y = __logf(fmaxf(acc[9],  1e-10f));
    r2.z = __logf(fmaxf(acc[10], 1e-10f));
    r2.w = __logf(fmaxf(acc[11], 1e-10f));
    r3.x = __logf(fmaxf(acc[12], 1e-10f));
    r3.y = __logf(fmaxf(acc[13], 1e-10f));
    r3.z = __logf(fmaxf(acc[14], 1e-10f));
    r3.w = __logf(fmaxf(acc[15], 1e-10f));

    const int row = nids[n];
    float* op = out + (size_t)row * BB + chunk * CHUNK_COLS + l4 * 16;
    __builtin_nontemporal_store(r0, reinterpret_cast<f32x4*>(op));
    __builtin_nontemporal_store(r1, reinterpret_cast<f32x4*>(op + 4));
    __builtin_nontemporal_store(r2, reinterpret_cast<f32x4*>(op + 8));
    __builtin_nontemporal_store(r3, reinterpret_cast<f32x4*>(op + 12));
}

// ---- fallback (ws too small): standalone fp32 version ----
__global__ __launch_bounds__(256, 2)
void sum_layer_fallback(const float* __restrict__ element_mars,
                        const float* __restrict__ params,
                        const int* __restrict__ nids,
                        const int* __restrict__ cids,
                        const int* __restrict__ pids,
                        float* __restrict__ out)
{
    const int tid  = threadIdx.x;
    const int wave = tid >> 6;
    const int lane = tid & 63;

    __shared__ int   s_cid[4][EE];
    __shared__ float s_w[4][EE];
    if (tid < 4 * EE) {
        const int wi = tid >> 5, e = tid & (EE - 1);
        const int gn = blockIdx.x * 4 + wi;
        s_cid[wi][e] = cids[gn * EE + e];
        s_w[wi][e]   = params[pids[gn * EE + e]];
    }
    __syncthreads();

    const int n = blockIdx.x * 4 + wave;
    float4 acc = make_float4(0.f, 0.f, 0.f, 0.f);
#pragma unroll
    for (int e = 0; e < EE; ++e) {
        const float4 v = *reinterpret_cast<const float4*>(
            element_mars + (size_t)s_cid[wave][e] * BB + 4 * lane);
        const float w = s_w[wave][e];
        acc.x = fmaf(__expf(v.x), w, acc.x);
        acc.y = fmaf(__expf(v.y), w, acc.y);
        acc.z = fmaf(__expf(v.z), w, acc.z);
        acc.w = fmaf(__expf(v.w), w, acc.w);
    }
    float4 r;
    r.x = __logf(fmaxf(acc.x, 1e-10f));
    r.y = __logf(fmaxf(acc.y, 1e-10f));
    r.z = __logf(fmaxf(acc.z, 1e-10f));
    r.w = __logf(fmaxf(acc.w, 1e-10f));
    *reinterpret_cast<float4*>(out + (size_t)nids[n] * BB + 4 * lane) = r;
}

extern "C" void kernel_launch(void* const* d_in, const int* in_sizes, int n_in,
                              void* d_out, int out_size, void* d_ws, size_t ws_size,
                              hipStream_t stream) {
    // inputs: node_mars[N,B], element_mars[MAX_ELS,B], params[N*E],
    //         nids[N], cids[N,E], pids[N,E]
    const float* element_mars = (const float*)d_in[1];
    const float* params       = (const float*)d_in[2];
    const int*   nids         = (const int*)d_in[3];
    const int*   cids         = (const int*)d_in[4];
    const int*   pids         = (const int*)d_in[5];
    float*       out          = (float*)d_out;

    const size_t g_bytes  = (size_t)NCHUNK * SLICE_BYTES;           // 16MB fp8
    const size_t wc_bytes = (size_t)NN * EE * sizeof(unsigned int); // 4MB

    if (ws_size >= g_bytes + wc_bytes) {
        unsigned char* G  = (unsigned char*)d_ws;
        unsigned int*  WC = (unsigned int*)((char*)d_ws + g_bytes);

        // 4096 exp-role blocks + 4096 wc-role blocks
        prep_kernel<<<8192, 256, 0, stream>>>(
            (const float4*)element_mars, params, cids, pids, G, WC);
        sum_main_kernel<<<(NN / NPB) * NCHUNK, 256, 0, stream>>>(G, WC, nids, out);
    } else {
        sum_layer_fallback<<<NN / 4, 256, 0, stream>>>(
            element_mars, params, nids, cids, pids, out);
    }
}

// Round 5
// 164.944 us; speedup vs baseline: 1.1299x; 1.1299x over previous
//
#include <hip/hip_runtime.h>
#include <hip/hip_fp8.h>
#include <hip/hip_fp16.h>

// SumLayer: weighted logsumexp over E children per node.
// N=32768, E=32, B=256, MAX_ELS=65536.
//
// R8 design. History:
//  R0-R2: fetch-bound (3.7 TB/s L2-miss). R3: fp8 G (16MB). R4: chunk-major
//  G[chunk][row] + XCD slicing + WC=u16 cid|f16 w -> FETCH 337->25MB, 44us.
//  R5: "16-deep pipeline" -> null, VGPR=36: compiler sank loads to uses.
//  R6: 64B requests (CHUNK_COLS=64, NCHUNK=4): ~40us (-15%). Latency math:
//  0.17 req/cyc/CU == ~64 in-flight/CU / ~300cyc L2 -> LATENCY bound at
//  compiler-chosen depth ~4.
//  R7: no-LDS + nt WC loads + named-reg pipeline -> REGRESSED 56.6us:
//  nt defeated caching (FETCH 25->77MB, HBM-latency first dep) and VGPR=56
//  proved the scheduler collapsed the pipeline AGAIN.
// R8: R6 structure + pipeline that SURVIVES compilation:
//  - WC via LDS (stride-36 rows, ds_read_b128, cached loads; no nt on reads)
//  - all 32 wc -> regs upfront; 8 lanes/node x uint2 (still one 64B req/(n,e))
//  - 2x8 double-buffered gathers, sched_barrier(0) after each issue group ->
//    16 outstanding VMEM reads/wave pinned in the .s; compiler emits counted
//    vmcnt(8) before each consume group. launch_bounds(256,4).
// Predicted: sum_main ~40 -> 18-26us, FETCH ~45-55MB, total ~150-162us.

constexpr int NN = 32768;
constexpr int EE = 32;
constexpr int BB = 256;
constexpr int MAX_ELS = 65536;

constexpr int NCHUNK = 4;                 // column chunks; slice on 2 XCDs
constexpr int CHUNK_COLS = 64;            // fp8 bytes per row per chunk
constexpr size_t SLICE_BYTES = (size_t)MAX_ELS * CHUNK_COLS;  // 4 MB
constexpr int NPB = 32;                   // nodes per block (main kernel)

typedef float floatx2 __attribute__((ext_vector_type(2)));
typedef float f32x4 __attribute__((ext_vector_type(4)));
typedef unsigned int u32x4 __attribute__((ext_vector_type(4)));

__device__ inline int pack4_fp8(float4 v) {
    const int a = __hip_cvt_float_to_fp8(__expf(v.x), __HIP_SATFINITE, __HIP_E4M3);
    const int b = __hip_cvt_float_to_fp8(__expf(v.y), __HIP_SATFINITE, __HIP_E4M3);
    const int c = __hip_cvt_float_to_fp8(__expf(v.z), __HIP_SATFINITE, __HIP_E4M3);
    const int d = __hip_cvt_float_to_fp8(__expf(v.w), __HIP_SATFINITE, __HIP_E4M3);
    return a | (b << 8) | (c << 16) | (d << 24);
}

// ---- merged pre-pass ----
// blocks [0,4096):  G[c][r][0..63] = fp8(exp(element_mars[r][c*64..+63]))
// blocks [4096,8192): WC[i] = (cids[i] as u16) | (f16(params[pids[i]]) << 16)
__global__ __launch_bounds__(256)
void prep_kernel(const float4* __restrict__ em, const float* __restrict__ params,
                 const int* __restrict__ cids, const int* __restrict__ pids,
                 unsigned char* __restrict__ G, unsigned int* __restrict__ WC)
{
    if (blockIdx.x < 4096) {
        const int wid  = blockIdx.x * 4 + (threadIdx.x >> 6);
        const int lane = threadIdx.x & 63;
        const int c    = wid & 3;
        const int rg   = wid >> 2;                  // [0, 4096)
        const int r    = rg * 16 + (lane >> 2);
        const int q    = lane & 3;

        const float4* src = em + (size_t)r * 64 + c * 16 + q * 4;
        const float4 v0 = src[0], v1 = src[1], v2 = src[2], v3 = src[3];
        int4 o;
        o.x = pack4_fp8(v0);
        o.y = pack4_fp8(v1);
        o.z = pack4_fp8(v2);
        o.w = pack4_fp8(v3);
        *reinterpret_cast<int4*>(G + (size_t)c * SLICE_BYTES
                                   + (size_t)r * CHUNK_COLS + q * 16) = o;
    } else {
        const int i = (blockIdx.x - 4096) * 256 + threadIdx.x;
        const unsigned int cid = (unsigned int)cids[i] & 0xFFFFu;   // MAX_ELS = 2^16
        const float w = params[pids[i]];
        const unsigned int h = (unsigned int)__half_as_ushort(__float2half(w));
        WC[i] = cid | (h << 16);
    }
}

// ---- main: 32 nodes/block x 64 cols; chunk = blockIdx%4 -> slice on 2 XCDs ----
// 8 nodes/wave, 8 lanes/node, uint2 (8B) per lane = ONE 64B request/(node,e).
// 2x8 double-buffered gather pipeline, pinned with sched_barrier(0).
__global__ __launch_bounds__(256, 4)
void sum_main_kernel(const unsigned char* __restrict__ G, const unsigned int* __restrict__ WC,
                     const int* __restrict__ nids, float* __restrict__ out)
{
    const int chunk = blockIdx.x & (NCHUNK - 1);
    const int g     = blockIdx.x >> 2;          // node-group of 32
    const int tid   = threadIdx.x;

    // 32 nodes x 32 packed (cid,w); row stride 36 u32 -> b128-aligned rows,
    // distinct banks across the 8 nodes of a wave (4*nl mod 32 all distinct).
    __shared__ unsigned int s_wc[NPB * 36];
    {
        const u32x4 v = reinterpret_cast<const u32x4*>(WC)[g * 256 + tid];
        unsigned int* p = s_wc + (tid >> 3) * 36 + (tid & 7) * 4;
        p[0] = v.x; p[1] = v.y; p[2] = v.z; p[3] = v.w;
    }
    __syncthreads();

    const int lane = tid & 63;
    const int nl   = (tid >> 6) * 8 + (lane >> 3);  // node-local 0..31
    const int l8   = lane & 7;                      // 8 cols of the 64-col slice
    const int n    = g * NPB + nl;
    const unsigned char* Gs = G + (size_t)chunk * SLICE_BYTES + l8 * 8;

    // all 32 wc entries -> 8 register vectors (ds_read_b128 x8, done once)
    const u32x4* wrow = reinterpret_cast<const u32x4*>(s_wc + nl * 36);
    const u32x4 w0 = wrow[0], w1 = wrow[1], w2 = wrow[2], w3 = wrow[3];
    const u32x4 w4 = wrow[4], w5 = wrow[5], w6 = wrow[6], w7 = wrow[7];

    float acc[8] = {0.f, 0.f, 0.f, 0.f, 0.f, 0.f, 0.f, 0.f};

#define LDG2(WCE) (*reinterpret_cast<const uint2*>( \
        Gs + ((size_t)((WCE) & 0xFFFFu) << 6)))

#define FMAV(U, WCE) do {                                                       \
    const float w_ = __half2float(__ushort_as_half(                             \
        (unsigned short)((WCE) >> 16)));                                        \
    const floatx2 p0 = __builtin_amdgcn_cvt_pk_f32_fp8((U).x, false);           \
    const floatx2 p1 = __builtin_amdgcn_cvt_pk_f32_fp8((U).x, true);            \
    const floatx2 p2 = __builtin_amdgcn_cvt_pk_f32_fp8((U).y, false);           \
    const floatx2 p3 = __builtin_amdgcn_cvt_pk_f32_fp8((U).y, true);            \
    acc[0] = fmaf(p0.x, w_, acc[0]);                                            \
    acc[1] = fmaf(p0.y, w_, acc[1]);                                            \
    acc[2] = fmaf(p1.x, w_, acc[2]);                                            \
    acc[3] = fmaf(p1.y, w_, acc[3]);                                            \
    acc[4] = fmaf(p2.x, w_, acc[4]);                                            \
    acc[5] = fmaf(p2.y, w_, acc[5]);                                            \
    acc[6] = fmaf(p3.x, w_, acc[6]);                                            \
    acc[7] = fmaf(p3.y, w_, acc[7]);                                            \
} while (0)

    uint2 a0, a1, a2, a3, a4, a5, a6, a7;
    uint2 b0, b1, b2, b3, b4, b5, b6, b7;

    // issue group A (e=0..7) -- pinned: cannot sink past the barrier
    a0 = LDG2(w0.x); a1 = LDG2(w0.y); a2 = LDG2(w0.z); a3 = LDG2(w0.w);
    a4 = LDG2(w1.x); a5 = LDG2(w1.y); a6 = LDG2(w1.z); a7 = LDG2(w1.w);
    __builtin_amdgcn_sched_barrier(0);
    // issue group B (e=8..15) -> 16 outstanding
    b0 = LDG2(w2.x); b1 = LDG2(w2.y); b2 = LDG2(w2.z); b3 = LDG2(w2.w);
    b4 = LDG2(w3.x); b5 = LDG2(w3.y); b6 = LDG2(w3.z); b7 = LDG2(w3.w);
    __builtin_amdgcn_sched_barrier(0);

    // consume A (vmcnt(8)), then refill A (e=16..23)
    FMAV(a0, w0.x); FMAV(a1, w0.y); FMAV(a2, w0.z); FMAV(a3, w0.w);
    FMAV(a4, w1.x); FMAV(a5, w1.y); FMAV(a6, w1.z); FMAV(a7, w1.w);
    a0 = LDG2(w4.x); a1 = LDG2(w4.y); a2 = LDG2(w4.z); a3 = LDG2(w4.w);
    a4 = LDG2(w5.x); a5 = LDG2(w5.y); a6 = LDG2(w5.z); a7 = LDG2(w5.w);
    __builtin_amdgcn_sched_barrier(0);

    // consume B (vmcnt(8)), then refill B (e=24..31)
    FMAV(b0, w2.x); FMAV(b1, w2.y); FMAV(b2, w2.z); FMAV(b3, w2.w);
    FMAV(b4, w3.x); FMAV(b5, w3.y); FMAV(b6, w3.z); FMAV(b7, w3.w);
    b0 = LDG2(w6.x); b1 = LDG2(w6.y); b2 = LDG2(w6.z); b3 = LDG2(w6.w);
    b4 = LDG2(w7.x); b5 = LDG2(w7.y); b6 = LDG2(w7.z); b7 = LDG2(w7.w);
    __builtin_amdgcn_sched_barrier(0);

    // drain
    FMAV(a0, w4.x); FMAV(a1, w4.y); FMAV(a2, w4.z); FMAV(a3, w4.w);
    FMAV(a4, w5.x); FMAV(a5, w5.y); FMAV(a6, w5.z); FMAV(a7, w5.w);
    FMAV(b0, w6.x); FMAV(b1, w6.y); FMAV(b2, w6.z); FMAV(b3, w6.w);
    FMAV(b4, w7.x); FMAV(b5, w7.y); FMAV(b6, w7.z); FMAV(b7, w7.w);

#undef LDG2
#undef FMAV

    f32x4 r0, r1;
    r0.x = __logf(fmaxf(acc[0], 1e-10f));
    r0.y = __logf(fmaxf(acc[1], 1e-10f));
    r0.z = __logf(fmaxf(acc[2], 1e-10f));
    r0.w = __logf(fmaxf(acc[3], 1e-10f));
    r1.x = __logf(fmaxf(acc[4], 1e-10f));
    r1.y = __logf(fmaxf(acc[5], 1e-10f));
    r1.z = __logf(fmaxf(acc[6], 1e-10f));
    r1.w = __logf(fmaxf(acc[7], 1e-10f));

    const int row = nids[n];
    float* op = out + (size_t)row * BB + chunk * CHUNK_COLS + l8 * 8;
    __builtin_nontemporal_store(r0, reinterpret_cast<f32x4*>(op));
    __builtin_nontemporal_store(r1, reinterpret_cast<f32x4*>(op + 4));
}

// ---- fallback (ws too small): standalone fp32 version ----
__global__ __launch_bounds__(256, 2)
void sum_layer_fallback(const float* __restrict__ element_mars,
                        const float* __restrict__ params,
                        const int* __restrict__ nids,
                        const int* __restrict__ cids,
                        const int* __restrict__ pids,
                        float* __restrict__ out)
{
    const int tid  = threadIdx.x;
    const int wave = tid >> 6;
    const int lane = tid & 63;

    __shared__ int   s_cid[4][EE];
    __shared__ float s_w[4][EE];
    if (tid < 4 * EE) {
        const int wi = tid >> 5, e = tid & (EE - 1);
        const int gn = blockIdx.x * 4 + wi;
        s_cid[wi][e] = cids[gn * EE + e];
        s_w[wi][e]   = params[pids[gn * EE + e]];
    }
    __syncthreads();

    const int n = blockIdx.x * 4 + wave;
    float4 acc = make_float4(0.f, 0.f, 0.f, 0.f);
#pragma unroll
    for (int e = 0; e < EE; ++e) {
        const float4 v = *reinterpret_cast<const float4*>(
            element_mars + (size_t)s_cid[wave][e] * BB + 4 * lane);
        const float w = s_w[wave][e];
        acc.x = fmaf(__expf(v.x), w, acc.x);
        acc.y = fmaf(__expf(v.y), w, acc.y);
        acc.z = fmaf(__expf(v.z), w, acc.z);
        acc.w = fmaf(__expf(v.w), w, acc.w);
    }
    float4 r;
    r.x = __logf(fmaxf(acc.x, 1e-10f));
    r.y = __logf(fmaxf(acc.y, 1e-10f));
    r.z = __logf(fmaxf(acc.z, 1e-10f));
    r.w = __logf(fmaxf(acc.w, 1e-10f));
    *reinterpret_cast<float4*>(out + (size_t)nids[n] * BB + 4 * lane) = r;
}

extern "C" void kernel_launch(void* const* d_in, const int* in_sizes, int n_in,
                              void* d_out, int out_size, void* d_ws, size_t ws_size,
                              hipStream_t stream) {
    // inputs: node_mars[N,B], element_mars[MAX_ELS,B], params[N*E],
    //         nids[N], cids[N,E], pids[N,E]
    const float* element_mars = (const float*)d_in[1];
    const float* params       = (const float*)d_in[2];
    const int*   nids         = (const int*)d_in[3];
    const int*   cids         = (const int*)d_in[4];
    const int*   pids         = (const int*)d_in[5];
    float*       out          = (float*)d_out;

    const size_t g_bytes  = (size_t)NCHUNK * SLICE_BYTES;           // 16MB fp8
    const size_t wc_bytes = (size_t)NN * EE * sizeof(unsigned int); // 4MB

    if (ws_size >= g_bytes + wc_bytes) {
        unsigned char* G  = (unsigned char*)d_ws;
        unsigned int*  WC = (unsigned int*)((char*)d_ws + g_bytes);

        // 4096 exp-role blocks + 4096 wc-role blocks
        prep_kernel<<<8192, 256, 0, stream>>>(
            (const float4*)element_mars, params, cids, pids, G, WC);
        sum_main_kernel<<<(NN / NPB) * NCHUNK, 256, 0, stream>>>(G, WC, nids, out);
    } else {
        sum_layer_fallback<<<NN / 4, 256, 0, stream>>>(
            element_mars, params, nids, cids, pids, out);
    }
}